// Round 10
// baseline (270.241 us; speedup 1.0000x reference)
//
#include <hip/hip_runtime.h>
#include <hip/hip_bf16.h>
#include <hip/hip_fp16.h>

// Problem constants (match reference)
constexpr int IMG_ = 256;
constexpr int M_   = 1920;   // N_SHOTS * N_SAMPLES
constexpr int B_   = 64;
constexpr int MI_  = M_ * IMG_;          // 491520 elements per phase table
constexpr int IMG2 = IMG_ * IMG_;        // 65536

typedef _Float16 half8 __attribute__((ext_vector_type(8)));
typedef float    floatx4 __attribute__((ext_vector_type(4)));

// global -> LDS direct copy, 16B per lane; LDS dest is wave-uniform base + lane*16
__device__ __forceinline__ void gll16(const _Float16* g, _Float16* l) {
  __builtin_amdgcn_global_load_lds(
      (const __attribute__((address_space(1))) void*)g,
      (__attribute__((address_space(3))) void*)l, 16, 0, 0);
}

// ---------------------------------------------------------------------------
// prep_k: fused {phase1 | phase2 | x-transpose} by blockIdx range (r9 version:
// PH1 writes only the Ax table; fwd epilogue reads the transposed aytc).
// ---------------------------------------------------------------------------
constexpr int PH1_N = MI_ / 256;          // 1920
constexpr int PH2_N = 8 * IMG_;           // 2048
constexpr int XT_N  = 8 * 8 * B_;         // 4096

__global__ __launch_bounds__(256) void prep_k(
    const float* __restrict__ samples,
    const float* __restrict__ xr, const float* __restrict__ xi,
    _Float16* __restrict__ axh_r, _Float16* __restrict__ axh_i,
    _Float16* __restrict__ axtc_r, _Float16* __restrict__ axtc_i,
    _Float16* __restrict__ aytc_r, _Float16* __restrict__ aytc_i,
    _Float16* __restrict__ xth_r, _Float16* __restrict__ xth_i) {
  __shared__ float tr[32][33], ti[32][33];
  const int t = threadIdx.x;
  const int n = blockIdx.x;

  if (n < PH1_N) {
    // Ax table, natural layout [m][i] (fwd A-operand)
    int idx = n * 256 + t;
    int m = idx >> 8;
    int i = idx & 255;
    float g  = (float)i - 128.0f;
    float kx = samples[2 * m + 0];
    float sx, cx;
    sincospif(-2.0f * kx * g, &sx, &cx);
    axh_r[idx] = (_Float16)cx; axh_i[idx] = (_Float16)sx;
  } else if (n < PH1_N + PH2_N) {
    // transposed, pre-conjugated tables [i][m] (adj operands + fwd epilogue)
    int nn = n - PH1_N;
    int m = (nn & 7) * 256 + t;
    int i = nn >> 3;
    if (m < M_) {               // guard: m decode spans 2048 > M_
      float g  = (float)i - 128.0f;
      float kx = samples[2 * m + 0];
      float ky = samples[2 * m + 1];
      float sx, cx, sy, cy;
      sincospif(-2.0f * kx * g, &sx, &cx);
      sincospif(-2.0f * ky * g, &sy, &cy);
      int o = i * M_ + m;
      axtc_r[o] = (_Float16)cx; axtc_i[o] = (_Float16)(-sx);
      aytc_r[o] = (_Float16)cy; aytc_i[o] = (_Float16)(-sy);
    }
  } else {
    int nn = n - PH1_N - PH2_N;
    const int b  = nn >> 6;
    const int i0 = (nn & 7) * 32, j0 = ((nn >> 3) & 7) * 32;
    const int r = t >> 5, c = t & 31;
#pragma unroll
    for (int k = 0; k < 4; ++k) {
      int row = r + k * 8;
      tr[row][c] = xr[(size_t)b * IMG2 + (i0 + row) * IMG_ + j0 + c];
      ti[row][c] = xi[(size_t)b * IMG2 + (i0 + row) * IMG_ + j0 + c];
    }
    __syncthreads();
#pragma unroll
    for (int k = 0; k < 4; ++k) {
      int row = r + k * 8;
      xth_r[(size_t)b * IMG2 + (j0 + row) * IMG_ + i0 + c] = (_Float16)tr[c][row];
      xth_i[(size_t)b * IMG2 + (j0 + row) * IMG_ + i0 + c] = (_Float16)ti[c][row];
    }
  }
}

// ---------------------------------------------------------------------------
// LDS swizzle (both GEMMs), per 32-half (64B) row of 4 16B chunks: physical
// chunk p of row r holds logical chunk p ^ ((r>>1)&3). Staging via
// global_load_lds writes lane-linear with pre-swizzled global source;
// ds_read_b128 frags read phys chunk q ^ ((lr>>1)&3). Zero bank conflicts
// (measured r1-r9).
// ---------------------------------------------------------------------------

// ---------------------------------------------------------------------------
// fwd_k: ROUND-10 = r5's 16-step structure (both jc halves per block; proven
// correct, fwd-alone 109 us) + r9's vectorized epilogue (proven -7.7 us).
// Eliminates comb_k + kpart: block writes FINAL kwh with density applied.
//   kw[b,m] = density[m] * sum_j Ay[m,j] * (sum_i Ax[m,i] * X_b[i,j])
// (256,3) + full unroll; residual scratch WRITE is a known benign spill (the
// no-spill variant r6 collapsed occupancy, 171 us). Streaming per-mt epilogue
// parks per-wave partials in scr; jc=0 runs at s==7 overlapping staging.
// Grid 1920 1-D XCD-grouped: xcd = n&7, 30 consecutive blocks share b.
// ---------------------------------------------------------------------------
__global__ __launch_bounds__(256, 3) void fwd_k(
    const _Float16* __restrict__ axh_r, const _Float16* __restrict__ axh_i,
    const _Float16* __restrict__ aytc_r, const _Float16* __restrict__ aytc_i,
    const _Float16* __restrict__ xth_r, const _Float16* __restrict__ xth_i,
    const float* __restrict__ density,
    _Float16* __restrict__ kwh_r, _Float16* __restrict__ kwh_i) {
  __shared__ _Float16 lds[2][12288];   // 48 KB staging
  __shared__ float2 scr[4][64];        // 2 KB per-wave m-partials

  const int t  = threadIdx.x;
  const int w  = t >> 6;
  const int l  = t & 63;
  const int lr = l & 15;   // frag row within 16-tile; C col (j)
  const int q  = l >> 4;   // k-chunk; C row group (m)

  const int n   = blockIdx.x;        // 0..1919
  const int xcd = n & 7;
  const int r   = n >> 3;            // 0..239
  const int b   = xcd + 8 * (r / 30);
  const int m0  = (r % 30) * 64;

  const int srow   = l >> 2;                      // staging row within 16
  const int schunk = (l & 3) ^ ((l >> 3) & 3);    // pre-swizzled global chunk
  const int gA     = srow * IMG_ + schunk * 8;    // halfs
  const int rc     = (q ^ ((lr >> 1) & 3)) << 3;  // frag-read swizzled chunk

  const floatx4 z4 = {0.f, 0.f, 0.f, 0.f};
  floatx4 accr[4][2], acci[4][2];
#pragma unroll
  for (int mt = 0; mt < 4; ++mt)
#pragma unroll
    for (int jt = 0; jt < 2; ++jt) { accr[mt][jt] = z4; acci[mt][jt] = z4; }

  auto stage = [&](int buf, int s) {
    const int jc  = s >> 3;
    const int col = (s & 7) * 32;
    _Float16* L = lds[buf];
    const size_t offA = (size_t)(m0 + w * 16) * IMG_ + col + gA;
    gll16(axh_r + offA, L + 0    + w * 512);
    gll16(axh_i + offA, L + 2048 + w * 512);
    const size_t offB = (size_t)b * IMG2 + (size_t)(jc * 128 + w * 32) * IMG_ + col + gA;
    gll16(xth_r + offB,             L + 4096 + w * 1024);
    gll16(xth_r + offB + 16 * IMG_, L + 4096 + w * 1024 + 512);
    gll16(xth_i + offB,             L + 8192 + w * 1024);
    gll16(xth_i + offB + 16 * IMG_, L + 8192 + w * 1024 + 512);
  };

  auto compute = [&](int buf) {
    const _Float16* L = lds[buf];
    half8 br[2], bi[2], nbi[2];
#pragma unroll
    for (int jt = 0; jt < 2; ++jt) {
      const int ro = (w * 32 + jt * 16 + lr) * 32 + rc;
      br[jt]  = *(const half8*)&L[4096 + ro];
      bi[jt]  = *(const half8*)&L[8192 + ro];
      nbi[jt] = -bi[jt];
    }
#pragma unroll
    for (int mt = 0; mt < 4; ++mt) {
      const int ro = (mt * 16 + lr) * 32 + rc;
      half8 ar = *(const half8*)&L[0 + ro];
      half8 ai = *(const half8*)&L[2048 + ro];
#pragma unroll
      for (int jt = 0; jt < 2; ++jt) {
        accr[mt][jt] = __builtin_amdgcn_mfma_f32_16x16x32_f16(ar, br[jt],  accr[mt][jt], 0, 0, 0);
        accr[mt][jt] = __builtin_amdgcn_mfma_f32_16x16x32_f16(ai, nbi[jt], accr[mt][jt], 0, 0, 0);
        acci[mt][jt] = __builtin_amdgcn_mfma_f32_16x16x32_f16(ar, bi[jt],  acci[mt][jt], 0, 0, 0);
        acci[mt][jt] = __builtin_amdgcn_mfma_f32_16x16x32_f16(ai, br[jt],  acci[mt][jt], 0, 0, 0);
      }
    }
  };

  // Streaming vectorized epilogue (r9 loads + r5 scr parking): per mt, fold
  // the Ay-weighted j-sum (Ay from transposed table: yr=aytc_r[j][m..m+3],
  // yi=-aytc_i[j][m..m+3] — two 8B loads per (mt,jt)), shfl-reduce over the
  // 16 j-lanes, park in scr. Only 8 f32 live at a time.
  auto epi = [&](int jc) {
#pragma unroll
    for (int mt = 0; mt < 4; ++mt) {
      const int mb = m0 + mt * 16 + q * 4;
      float kr[4] = {}, ki[4] = {};
#pragma unroll
      for (int jt = 0; jt < 2; ++jt) {
        const int j = jc * 128 + w * 32 + jt * 16 + lr;
        const __half2* yr2 = (const __half2*)&aytc_r[(size_t)j * M_ + mb];
        const __half2* yi2 = (const __half2*)&aytc_i[(size_t)j * M_ + mb];
        const __half2 yr01 = yr2[0], yr23 = yr2[1];
        const __half2 yi01 = yi2[0], yi23 = yi2[1];
        const float yrv[4] = {__low2float(yr01), __high2float(yr01),
                              __low2float(yr23), __high2float(yr23)};
        const float yiv[4] = {-__low2float(yi01), -__high2float(yi01),
                              -__low2float(yi23), -__high2float(yi23)};
#pragma unroll
        for (int reg = 0; reg < 4; ++reg) {
          const float tr = accr[mt][jt][reg], ti = acci[mt][jt][reg];
          kr[reg] = fmaf(yrv[reg], tr, fmaf(-yiv[reg], ti, kr[reg]));
          ki[reg] = fmaf(yrv[reg], ti, fmaf(yiv[reg], tr, ki[reg]));
        }
        accr[mt][jt] = z4;
        acci[mt][jt] = z4;
      }
#pragma unroll
      for (int reg = 0; reg < 4; ++reg)
#pragma unroll
        for (int off = 1; off < 16; off <<= 1) {
          kr[reg] += __shfl_xor(kr[reg], off);
          ki[reg] += __shfl_xor(ki[reg], off);
        }
      if (lr == 0) {
#pragma unroll
        for (int reg = 0; reg < 4; ++reg) {
          const int ml = mt * 16 + q * 4 + reg;
          if (jc == 0) {
            scr[w][ml] = make_float2(kr[reg], ki[reg]);
          } else {
            float2 p = scr[w][ml];
            scr[w][ml] = make_float2(p.x + kr[reg], p.y + ki[reg]);
          }
        }
      }
    }
  };

  stage(0, 0);
  __syncthreads();               // implicit vmcnt(0) drains global_load_lds
#pragma unroll
  for (int s = 0; s < 16; ++s) {
    const int buf = s & 1;
    if (s < 15) stage(buf ^ 1, s + 1);    // next-tile loads overlap MFMA
    compute(buf);
    if (s == 7) epi(0);                   // overlaps in-flight stage(8) loads
    __syncthreads();
  }
  epi(1);
  __syncthreads();

  // cross-wave combine (4 j-slices), density, final f16 kw write
  if (t < 64) {
    float sr = 0.f, si = 0.f;
#pragma unroll
    for (int ww = 0; ww < 4; ++ww) {
      const float2 p = scr[ww][t];
      sr += p.x; si += p.y;
    }
    const int m = m0 + t;
    const float d = density[m];
    kwh_r[b * M_ + m] = (_Float16)(sr * d);
    kwh_i[b * M_ + m] = (_Float16)(si * d);
  }
}

// ---------------------------------------------------------------------------
// adj_k: r3/r8/r9 version verbatim (best measured adj).
//   out[b,i,j] = (1/IMG^2) sum_m conj(Ax)[m,i] * kw[b,m] * conj(Ay)[m,j]
// Block 256 thr = 4 waves; block tile 64i x 128j; wave tile 64i x 32j.
// K = 1920 m, 60 double-buffered steps. Grid (4, 2, 64) = 512 blocks.
// ---------------------------------------------------------------------------
__global__ __launch_bounds__(256, 3) void adj_k(
    const _Float16* __restrict__ axtc_r, const _Float16* __restrict__ axtc_i,
    const _Float16* __restrict__ aytc_r, const _Float16* __restrict__ aytc_i,
    const _Float16* __restrict__ kwh_r, const _Float16* __restrict__ kwh_i,
    float* __restrict__ out) {
  __shared__ _Float16 lds[2][12288];   // 48 KB

  const int t  = threadIdx.x;
  const int w  = t >> 6;
  const int l  = t & 63;
  const int lr = l & 15;
  const int q  = l >> 4;
  const int b  = blockIdx.z;
  const int i0 = blockIdx.x * 64;
  const int j0 = blockIdx.y * 128;

  const int srow   = l >> 2;
  const int schunk = (l & 3) ^ ((l >> 3) & 3);
  const int gA     = srow * M_ + schunk * 8;      // A row stride = 1920 halfs
  const int rc     = (q ^ ((lr >> 1) & 3)) << 3;

  // W staging: thread -> (j-row = t>>1, m-half = t&1); swizzled b128 writes
  const int wrow = t >> 1;
  const int wh   = t & 1;
  const int wp   = (wrow >> 1) & 3;
  const int wc0  = ((2 * wh + 0) ^ wp) << 3;
  const int wc1  = ((2 * wh + 1) ^ wp) << 3;

  const floatx4 z4 = {0.f, 0.f, 0.f, 0.f};
  floatx4 accr[4][2], acci[4][2];
#pragma unroll
  for (int mt = 0; mt < 4; ++mt)
#pragma unroll
    for (int jt = 0; jt < 2; ++jt) { accr[mt][jt] = z4; acci[mt][jt] = z4; }

  uint4 Yr0, Yr1, Yi0, Yi1, Cr0, Cr1, Ci0, Ci1;

  auto stageA = [&](int buf, int s) {
    const int mc = s * 32;
    _Float16* L = lds[buf];
    const size_t off = (size_t)(i0 + w * 16) * M_ + mc + gA;
    gll16(axtc_r + off, L + 0    + w * 512);
    gll16(axtc_i + off, L + 2048 + w * 512);
  };

  auto loadW = [&](int s) {   // issue early; consumed by writeW after compute
    const int mc = s * 32 + wh * 16;
    const size_t oy = (size_t)(j0 + wrow) * M_ + mc;
    const size_t oc = (size_t)b * M_ + mc;
    Yr0 = *(const uint4*)&aytc_r[oy];  Yr1 = *(const uint4*)&aytc_r[oy + 8];
    Yi0 = *(const uint4*)&aytc_i[oy];  Yi1 = *(const uint4*)&aytc_i[oy + 8];
    Cr0 = *(const uint4*)&kwh_r[oc];   Cr1 = *(const uint4*)&kwh_r[oc + 8];
    Ci0 = *(const uint4*)&kwh_i[oc];   Ci1 = *(const uint4*)&kwh_i[oc + 8];
  };

  auto writeW = [&](int buf) {
    __half2 Wr0[4], Wi0[4], Wr1[4], Wi1[4];
    {
      const __half2* yr = (const __half2*)&Yr0; const __half2* yi = (const __half2*)&Yi0;
      const __half2* cr = (const __half2*)&Cr0; const __half2* ci = (const __half2*)&Ci0;
#pragma unroll
      for (int e = 0; e < 4; ++e) {
        Wr0[e] = __hsub2(__hmul2(cr[e], yr[e]), __hmul2(ci[e], yi[e]));
        Wi0[e] = __hfma2(cr[e], yi[e], __hmul2(ci[e], yr[e]));
      }
    }
    {
      const __half2* yr = (const __half2*)&Yr1; const __half2* yi = (const __half2*)&Yi1;
      const __half2* cr = (const __half2*)&Cr1; const __half2* ci = (const __half2*)&Ci1;
#pragma unroll
      for (int e = 0; e < 4; ++e) {
        Wr1[e] = __hsub2(__hmul2(cr[e], yr[e]), __hmul2(ci[e], yi[e]));
        Wi1[e] = __hfma2(cr[e], yi[e], __hmul2(ci[e], yr[e]));
      }
    }
    _Float16* Lr = lds[buf] + 4096;
    _Float16* Li = lds[buf] + 8192;
    const int rb = wrow * 32;
    *(uint4*)&Lr[rb + wc0] = *(const uint4*)&Wr0[0];
    *(uint4*)&Lr[rb + wc1] = *(const uint4*)&Wr1[0];
    *(uint4*)&Li[rb + wc0] = *(const uint4*)&Wi0[0];
    *(uint4*)&Li[rb + wc1] = *(const uint4*)&Wi1[0];
  };

  auto compute = [&](int buf) {
    const _Float16* L = lds[buf];
    half8 br[2], bi[2], nbi[2];
#pragma unroll
    for (int jt = 0; jt < 2; ++jt) {
      const int ro = (w * 32 + jt * 16 + lr) * 32 + rc;
      br[jt]  = *(const half8*)&L[4096 + ro];
      bi[jt]  = *(const half8*)&L[8192 + ro];
      nbi[jt] = -bi[jt];
    }
#pragma unroll
    for (int mt = 0; mt < 4; ++mt) {
      const int ro = (mt * 16 + lr) * 32 + rc;
      half8 ar = *(const half8*)&L[0 + ro];
      half8 ai = *(const half8*)&L[2048 + ro];
#pragma unroll
      for (int jt = 0; jt < 2; ++jt) {
        accr[mt][jt] = __builtin_amdgcn_mfma_f32_16x16x32_f16(ar, br[jt],  accr[mt][jt], 0, 0, 0);
        accr[mt][jt] = __builtin_amdgcn_mfma_f32_16x16x32_f16(ai, nbi[jt], accr[mt][jt], 0, 0, 0);
        acci[mt][jt] = __builtin_amdgcn_mfma_f32_16x16x32_f16(ar, bi[jt],  acci[mt][jt], 0, 0, 0);
        acci[mt][jt] = __builtin_amdgcn_mfma_f32_16x16x32_f16(ai, br[jt],  acci[mt][jt], 0, 0, 0);
      }
    }
  };

  loadW(0);
  stageA(0, 0);
  writeW(0);
  __syncthreads();
#pragma unroll 2
  for (int s = 0; s < 60; ++s) {
    const int buf = s & 1;
    if (s < 59) { stageA(buf ^ 1, s + 1); loadW(s + 1); }
    compute(buf);
    if (s < 59) writeW(buf ^ 1);
    __syncthreads();
  }

  const float sc = 1.0f / (float)IMG2;
#pragma unroll
  for (int mt = 0; mt < 4; ++mt)
#pragma unroll
    for (int jt = 0; jt < 2; ++jt) {
      const int jg = j0 + w * 32 + jt * 16 + lr;
#pragma unroll
      for (int reg = 0; reg < 4; ++reg) {
        const int ig = i0 + mt * 16 + q * 4 + reg;
        float2 v = make_float2(accr[mt][jt][reg] * sc, acci[mt][jt][reg] * sc);
        *(float2*)&out[((size_t)(b * IMG_ + ig) * IMG_ + jg) * 2] = v;
      }
    }
}

// ---------------------------------------------------------------------------
// Launch: prep, fwd, adj (3 kernels; comb_k + kpart eliminated).
// ---------------------------------------------------------------------------
extern "C" void kernel_launch(void* const* d_in, const int* in_sizes, int n_in,
                              void* d_out, int out_size, void* d_ws, size_t ws_size,
                              hipStream_t stream) {
  (void)in_sizes; (void)n_in; (void)out_size; (void)ws_size;

  const float* xr      = (const float*)d_in[0];
  const float* xi      = (const float*)d_in[1];
  const float* samples = (const float*)d_in[2];
  const float* density = (const float*)d_in[3];
  float* out = (float*)d_out;

  // ws layout (ayh slots retired; offsets kept stable)
  _Float16* f = (_Float16*)d_ws;
  _Float16* axh_r  = f + 0 * MI_;
  _Float16* axh_i  = f + 1 * MI_;
  _Float16* axtc_r = f + 4 * MI_;
  _Float16* axtc_i = f + 5 * MI_;
  _Float16* aytc_r = f + 6 * MI_;
  _Float16* aytc_i = f + 7 * MI_;
  _Float16* kwh_r  = f + 8 * MI_;
  _Float16* kwh_i  = kwh_r + B_ * M_;

  // X^T (f16) parked in d_out; fully consumed by fwd_k before adj_k overwrites.
  _Float16* xth_r = (_Float16*)d_out;
  _Float16* xth_i = xth_r + (size_t)B_ * IMG2;

  prep_k<<<PH1_N + PH2_N + XT_N, 256, 0, stream>>>(
      samples, xr, xi, axh_r, axh_i,
      axtc_r, axtc_i, aytc_r, aytc_i, xth_r, xth_i);
  fwd_k<<<1920, 256, 0, stream>>>(axh_r, axh_i, aytc_r, aytc_i,
                                  xth_r, xth_i, density, kwh_r, kwh_i);
  adj_k<<<dim3(4, 2, B_), 256, 0, stream>>>(axtc_r, axtc_i, aytc_r, aytc_i,
                                            kwh_r, kwh_i, out);
}

// Round 11
// 259.352 us; speedup vs baseline: 1.0420x; 1.0420x over previous
//
#include <hip/hip_runtime.h>
#include <hip/hip_bf16.h>
#include <hip/hip_fp16.h>

// Problem constants (match reference)
constexpr int IMG_ = 256;
constexpr int M_   = 1920;   // N_SHOTS * N_SAMPLES
constexpr int B_   = 64;
constexpr int MI_  = M_ * IMG_;          // 491520 elements per phase table
constexpr int IMG2 = IMG_ * IMG_;        // 65536

typedef _Float16 half8 __attribute__((ext_vector_type(8)));
typedef float    floatx4 __attribute__((ext_vector_type(4)));

// global -> LDS direct copy, 16B per lane; LDS dest is wave-uniform base + lane*16
__device__ __forceinline__ void gll16(const _Float16* g, _Float16* l) {
  __builtin_amdgcn_global_load_lds(
      (const __attribute__((address_space(1))) void*)g,
      (__attribute__((address_space(3))) void*)l, 16, 0, 0);
}

// ---------------------------------------------------------------------------
// prep_k: fused {phase1 | phase2 | x-transpose} by blockIdx range.
// PH1 writes only the Ax table (fwd epilogue reads the transposed aytc).
// ---------------------------------------------------------------------------
constexpr int PH1_N = MI_ / 256;          // 1920
constexpr int PH2_N = 8 * IMG_;           // 2048
constexpr int XT_N  = 8 * 8 * B_;         // 4096

__global__ __launch_bounds__(256) void prep_k(
    const float* __restrict__ samples,
    const float* __restrict__ xr, const float* __restrict__ xi,
    _Float16* __restrict__ axh_r, _Float16* __restrict__ axh_i,
    _Float16* __restrict__ axtc_r, _Float16* __restrict__ axtc_i,
    _Float16* __restrict__ aytc_r, _Float16* __restrict__ aytc_i,
    _Float16* __restrict__ xth_r, _Float16* __restrict__ xth_i) {
  __shared__ float tr[32][33], ti[32][33];
  const int t = threadIdx.x;
  const int n = blockIdx.x;

  if (n < PH1_N) {
    // Ax table, natural layout [m][i] (fwd A-operand)
    int idx = n * 256 + t;
    int m = idx >> 8;
    int i = idx & 255;
    float g  = (float)i - 128.0f;
    float kx = samples[2 * m + 0];
    float sx, cx;
    sincospif(-2.0f * kx * g, &sx, &cx);
    axh_r[idx] = (_Float16)cx; axh_i[idx] = (_Float16)sx;
  } else if (n < PH1_N + PH2_N) {
    // transposed, pre-conjugated tables [i][m] (adj operands + fwd epilogue)
    int nn = n - PH1_N;
    int m = (nn & 7) * 256 + t;
    int i = nn >> 3;
    if (m < M_) {               // guard: m decode spans 2048 > M_
      float g  = (float)i - 128.0f;
      float kx = samples[2 * m + 0];
      float ky = samples[2 * m + 1];
      float sx, cx, sy, cy;
      sincospif(-2.0f * kx * g, &sx, &cx);
      sincospif(-2.0f * ky * g, &sy, &cy);
      int o = i * M_ + m;
      axtc_r[o] = (_Float16)cx; axtc_i[o] = (_Float16)(-sx);
      aytc_r[o] = (_Float16)cy; aytc_i[o] = (_Float16)(-sy);
    }
  } else {
    int nn = n - PH1_N - PH2_N;
    const int b  = nn >> 6;
    const int i0 = (nn & 7) * 32, j0 = ((nn >> 3) & 7) * 32;
    const int r = t >> 5, c = t & 31;
#pragma unroll
    for (int k = 0; k < 4; ++k) {
      int row = r + k * 8;
      tr[row][c] = xr[(size_t)b * IMG2 + (i0 + row) * IMG_ + j0 + c];
      ti[row][c] = xi[(size_t)b * IMG2 + (i0 + row) * IMG_ + j0 + c];
    }
    __syncthreads();
#pragma unroll
    for (int k = 0; k < 4; ++k) {
      int row = r + k * 8;
      xth_r[(size_t)b * IMG2 + (j0 + row) * IMG_ + i0 + c] = (_Float16)tr[c][row];
      xth_i[(size_t)b * IMG2 + (j0 + row) * IMG_ + i0 + c] = (_Float16)ti[c][row];
    }
  }
}

// ---------------------------------------------------------------------------
// LDS swizzle (both GEMMs), per 32-half (64B) row of 4 16B chunks: physical
// chunk p of row r holds logical chunk p ^ ((r>>1)&3). Staging via
// global_load_lds writes lane-linear with pre-swizzled global source;
// ds_read_b128 frags read phys chunk q ^ ((lr>>1)&3). Zero bank conflicts
// (measured every round r1-r10).
// ---------------------------------------------------------------------------

// ---------------------------------------------------------------------------
// fwd_k: converged form (r9; fastest measured — 100.0 us steady, WRITE 21 MB).
// 8-step K-loop per jc-half (jc in grid), post-loop VECTORIZED epilogue (Ay
// from the transposed table: two 8B loads per (mt,jt); bit-identical since
// ayh_r==aytc_r, ayh_i==-aytc_i). (256,3) + full unroll; residual scratch is
// a benign spill — the no-spill variant (r6) halved occupancy and ran 171 us.
// 25-28% MfmaUtil here is the 2-barrier-per-K-step structural plateau; all
// source-level pipelining grafts on this structure measure neutral.
//   kpart[jc][b][m] = sum_{j in jc half} Ay[m,j] * (sum_i Ax[m,i] * X_b[i,j])
// Grid 3840 1-D XCD-grouped; block 64m x 128j (one jc), 8 k-steps.
// ---------------------------------------------------------------------------
__global__ __launch_bounds__(256, 3) void fwd_k(
    const _Float16* __restrict__ axh_r, const _Float16* __restrict__ axh_i,
    const _Float16* __restrict__ aytc_r, const _Float16* __restrict__ aytc_i,
    const _Float16* __restrict__ xth_r, const _Float16* __restrict__ xth_i,
    float2* __restrict__ kpart) {
  __shared__ _Float16 lds[2][12288];   // 48 KB

  const int t  = threadIdx.x;
  const int w  = t >> 6;
  const int l  = t & 63;
  const int lr = l & 15;   // frag row within 16-tile; C col (j)
  const int q  = l >> 4;   // k-chunk; C row group (m)

  const int n     = blockIdx.x;        // 0..3839
  const int r     = n >> 3;            // 0..479
  const int b     = (n & 7) + 8 * (r / 60);
  const int inner = r % 60;
  const int m0    = (inner % 30) * 64;
  const int jc    = inner / 30;
  const int j0    = jc * 128;

  const int srow   = l >> 2;                      // staging row within 16
  const int schunk = (l & 3) ^ ((l >> 3) & 3);    // pre-swizzled global chunk
  const int gA     = srow * IMG_ + schunk * 8;    // halfs
  const int rc     = (q ^ ((lr >> 1) & 3)) << 3;  // frag-read swizzled chunk

  const floatx4 z4 = {0.f, 0.f, 0.f, 0.f};
  floatx4 accr[4][2], acci[4][2];
#pragma unroll
  for (int mt = 0; mt < 4; ++mt)
#pragma unroll
    for (int jt = 0; jt < 2; ++jt) { accr[mt][jt] = z4; acci[mt][jt] = z4; }

  auto stage = [&](int buf, int s) {
    const int col = s * 32;
    _Float16* L = lds[buf];
    const size_t offA = (size_t)(m0 + w * 16) * IMG_ + col + gA;
    gll16(axh_r + offA, L + 0    + w * 512);
    gll16(axh_i + offA, L + 2048 + w * 512);
    const size_t offB = (size_t)b * IMG2 + (size_t)(j0 + w * 32) * IMG_ + col + gA;
    gll16(xth_r + offB,             L + 4096 + w * 1024);
    gll16(xth_r + offB + 16 * IMG_, L + 4096 + w * 1024 + 512);
    gll16(xth_i + offB,             L + 8192 + w * 1024);
    gll16(xth_i + offB + 16 * IMG_, L + 8192 + w * 1024 + 512);
  };

  auto compute = [&](int buf) {
    const _Float16* L = lds[buf];
    half8 br[2], bi[2], nbi[2];
#pragma unroll
    for (int jt = 0; jt < 2; ++jt) {
      const int ro = (w * 32 + jt * 16 + lr) * 32 + rc;
      br[jt]  = *(const half8*)&L[4096 + ro];
      bi[jt]  = *(const half8*)&L[8192 + ro];
      nbi[jt] = -bi[jt];
    }
#pragma unroll
    for (int mt = 0; mt < 4; ++mt) {
      const int ro = (mt * 16 + lr) * 32 + rc;
      half8 ar = *(const half8*)&L[0 + ro];
      half8 ai = *(const half8*)&L[2048 + ro];
#pragma unroll
      for (int jt = 0; jt < 2; ++jt) {
        accr[mt][jt] = __builtin_amdgcn_mfma_f32_16x16x32_f16(ar, br[jt],  accr[mt][jt], 0, 0, 0);
        accr[mt][jt] = __builtin_amdgcn_mfma_f32_16x16x32_f16(ai, nbi[jt], accr[mt][jt], 0, 0, 0);
        acci[mt][jt] = __builtin_amdgcn_mfma_f32_16x16x32_f16(ar, bi[jt],  acci[mt][jt], 0, 0, 0);
        acci[mt][jt] = __builtin_amdgcn_mfma_f32_16x16x32_f16(ai, br[jt],  acci[mt][jt], 0, 0, 0);
      }
    }
  };

  stage(0, 0);
  __syncthreads();               // implicit vmcnt(0) drains global_load_lds
#pragma unroll
  for (int s = 0; s < 8; ++s) {
    const int buf = s & 1;
    if (s < 7) stage(buf ^ 1, s + 1);    // next-tile loads overlap MFMA
    compute(buf);
    __syncthreads();
  }

  // Epilogue (once, post-loop): kacc[m] += sum_j Ay[m,j]*T[m,j]
  // Ay via transposed table: yr = aytc_r[j][m..m+3], yi = -aytc_i[j][m..m+3]
  float kr[4][4] = {}, ki[4][4] = {};
#pragma unroll
  for (int mt = 0; mt < 4; ++mt) {
    const int mb = m0 + mt * 16 + q * 4;
#pragma unroll
    for (int jt = 0; jt < 2; ++jt) {
      const int j = j0 + w * 32 + jt * 16 + lr;
      const __half2* yr2 = (const __half2*)&aytc_r[(size_t)j * M_ + mb];
      const __half2* yi2 = (const __half2*)&aytc_i[(size_t)j * M_ + mb];
      const __half2 yr01 = yr2[0], yr23 = yr2[1];
      const __half2 yi01 = yi2[0], yi23 = yi2[1];
      const float yrv[4] = {__low2float(yr01), __high2float(yr01),
                            __low2float(yr23), __high2float(yr23)};
      const float yiv[4] = {-__low2float(yi01), -__high2float(yi01),
                            -__low2float(yi23), -__high2float(yi23)};
#pragma unroll
      for (int reg = 0; reg < 4; ++reg) {
        const float tr = accr[mt][jt][reg], ti = acci[mt][jt][reg];
        kr[mt][reg] = fmaf(yrv[reg], tr, fmaf(-yiv[reg], ti, kr[mt][reg]));
        ki[mt][reg] = fmaf(yrv[reg], ti, fmaf(yiv[reg], tr, ki[mt][reg]));
      }
    }
  }

#pragma unroll
  for (int mt = 0; mt < 4; ++mt)
#pragma unroll
    for (int reg = 0; reg < 4; ++reg)
#pragma unroll
      for (int off = 1; off < 16; off <<= 1) {
        kr[mt][reg] += __shfl_xor(kr[mt][reg], off);
        ki[mt][reg] += __shfl_xor(ki[mt][reg], off);
      }

  float2* scr = (float2*)&lds[0][0];
  if (lr == 0) {
#pragma unroll
    for (int mt = 0; mt < 4; ++mt)
#pragma unroll
      for (int reg = 0; reg < 4; ++reg)
        scr[w * 64 + mt * 16 + q * 4 + reg] = make_float2(kr[mt][reg], ki[mt][reg]);
  }
  __syncthreads();
  if (t < 64) {
    float sr = 0.f, si = 0.f;
#pragma unroll
    for (int ww = 0; ww < 4; ++ww) {
      const float2 p = scr[ww * 64 + t];
      sr += p.x; si += p.y;
    }
    kpart[((size_t)jc * B_ + b) * M_ + m0 + t] = make_float2(sr, si);
  }
}

// ---------------------------------------------------------------------------
// Combine jc partials, apply density, convert to f16 kw.
// ---------------------------------------------------------------------------
__global__ __launch_bounds__(256) void comb_k(
    const float2* __restrict__ kpart, const float* __restrict__ density,
    _Float16* __restrict__ kwh_r, _Float16* __restrict__ kwh_i) {
  const int idx = blockIdx.x * 256 + threadIdx.x;
  if (idx >= B_ * M_) return;
  const int m = idx % M_;
  const float2 p0 = kpart[idx];
  const float2 p1 = kpart[(size_t)B_ * M_ + idx];
  const float d = density[m];
  kwh_r[idx] = (_Float16)((p0.x + p1.x) * d);
  kwh_i[idx] = (_Float16)((p0.y + p1.y) * d);
}

// ---------------------------------------------------------------------------
// adj_k: best measured adj (r3 structure, unchanged since).
//   out[b,i,j] = (1/IMG^2) sum_m conj(Ax)[m,i] * kw[b,m] * conj(Ay)[m,j]
// Block 256 thr = 4 waves; block tile 64i x 128j; wave tile 64i x 32j.
// K = 1920 m, 60 double-buffered steps. Grid (4, 2, 64) = 512 blocks.
// ---------------------------------------------------------------------------
__global__ __launch_bounds__(256, 3) void adj_k(
    const _Float16* __restrict__ axtc_r, const _Float16* __restrict__ axtc_i,
    const _Float16* __restrict__ aytc_r, const _Float16* __restrict__ aytc_i,
    const _Float16* __restrict__ kwh_r, const _Float16* __restrict__ kwh_i,
    float* __restrict__ out) {
  __shared__ _Float16 lds[2][12288];   // 48 KB

  const int t  = threadIdx.x;
  const int w  = t >> 6;
  const int l  = t & 63;
  const int lr = l & 15;
  const int q  = l >> 4;
  const int b  = blockIdx.z;
  const int i0 = blockIdx.x * 64;
  const int j0 = blockIdx.y * 128;

  const int srow   = l >> 2;
  const int schunk = (l & 3) ^ ((l >> 3) & 3);
  const int gA     = srow * M_ + schunk * 8;      // A row stride = 1920 halfs
  const int rc     = (q ^ ((lr >> 1) & 3)) << 3;

  // W staging: thread -> (j-row = t>>1, m-half = t&1); swizzled b128 writes
  const int wrow = t >> 1;
  const int wh   = t & 1;
  const int wp   = (wrow >> 1) & 3;
  const int wc0  = ((2 * wh + 0) ^ wp) << 3;
  const int wc1  = ((2 * wh + 1) ^ wp) << 3;

  const floatx4 z4 = {0.f, 0.f, 0.f, 0.f};
  floatx4 accr[4][2], acci[4][2];
#pragma unroll
  for (int mt = 0; mt < 4; ++mt)
#pragma unroll
    for (int jt = 0; jt < 2; ++jt) { accr[mt][jt] = z4; acci[mt][jt] = z4; }

  uint4 Yr0, Yr1, Yi0, Yi1, Cr0, Cr1, Ci0, Ci1;

  auto stageA = [&](int buf, int s) {
    const int mc = s * 32;
    _Float16* L = lds[buf];
    const size_t off = (size_t)(i0 + w * 16) * M_ + mc + gA;
    gll16(axtc_r + off, L + 0    + w * 512);
    gll16(axtc_i + off, L + 2048 + w * 512);
  };

  auto loadW = [&](int s) {   // issue early; consumed by writeW after compute
    const int mc = s * 32 + wh * 16;
    const size_t oy = (size_t)(j0 + wrow) * M_ + mc;
    const size_t oc = (size_t)b * M_ + mc;
    Yr0 = *(const uint4*)&aytc_r[oy];  Yr1 = *(const uint4*)&aytc_r[oy + 8];
    Yi0 = *(const uint4*)&aytc_i[oy];  Yi1 = *(const uint4*)&aytc_i[oy + 8];
    Cr0 = *(const uint4*)&kwh_r[oc];   Cr1 = *(const uint4*)&kwh_r[oc + 8];
    Ci0 = *(const uint4*)&kwh_i[oc];   Ci1 = *(const uint4*)&kwh_i[oc + 8];
  };

  auto writeW = [&](int buf) {
    __half2 Wr0[4], Wi0[4], Wr1[4], Wi1[4];
    {
      const __half2* yr = (const __half2*)&Yr0; const __half2* yi = (const __half2*)&Yi0;
      const __half2* cr = (const __half2*)&Cr0; const __half2* ci = (const __half2*)&Ci0;
#pragma unroll
      for (int e = 0; e < 4; ++e) {
        Wr0[e] = __hsub2(__hmul2(cr[e], yr[e]), __hmul2(ci[e], yi[e]));
        Wi0[e] = __hfma2(cr[e], yi[e], __hmul2(ci[e], yr[e]));
      }
    }
    {
      const __half2* yr = (const __half2*)&Yr1; const __half2* yi = (const __half2*)&Yi1;
      const __half2* cr = (const __half2*)&Cr1; const __half2* ci = (const __half2*)&Ci1;
#pragma unroll
      for (int e = 0; e < 4; ++e) {
        Wr1[e] = __hsub2(__hmul2(cr[e], yr[e]), __hmul2(ci[e], yi[e]));
        Wi1[e] = __hfma2(cr[e], yi[e], __hmul2(ci[e], yr[e]));
      }
    }
    _Float16* Lr = lds[buf] + 4096;
    _Float16* Li = lds[buf] + 8192;
    const int rb = wrow * 32;
    *(uint4*)&Lr[rb + wc0] = *(const uint4*)&Wr0[0];
    *(uint4*)&Lr[rb + wc1] = *(const uint4*)&Wr1[0];
    *(uint4*)&Li[rb + wc0] = *(const uint4*)&Wi0[0];
    *(uint4*)&Li[rb + wc1] = *(const uint4*)&Wi1[0];
  };

  auto compute = [&](int buf) {
    const _Float16* L = lds[buf];
    half8 br[2], bi[2], nbi[2];
#pragma unroll
    for (int jt = 0; jt < 2; ++jt) {
      const int ro = (w * 32 + jt * 16 + lr) * 32 + rc;
      br[jt]  = *(const half8*)&L[4096 + ro];
      bi[jt]  = *(const half8*)&L[8192 + ro];
      nbi[jt] = -bi[jt];
    }
#pragma unroll
    for (int mt = 0; mt < 4; ++mt) {
      const int ro = (mt * 16 + lr) * 32 + rc;
      half8 ar = *(const half8*)&L[0 + ro];
      half8 ai = *(const half8*)&L[2048 + ro];
#pragma unroll
      for (int jt = 0; jt < 2; ++jt) {
        accr[mt][jt] = __builtin_amdgcn_mfma_f32_16x16x32_f16(ar, br[jt],  accr[mt][jt], 0, 0, 0);
        accr[mt][jt] = __builtin_amdgcn_mfma_f32_16x16x32_f16(ai, nbi[jt], accr[mt][jt], 0, 0, 0);
        acci[mt][jt] = __builtin_amdgcn_mfma_f32_16x16x32_f16(ar, bi[jt],  acci[mt][jt], 0, 0, 0);
        acci[mt][jt] = __builtin_amdgcn_mfma_f32_16x16x32_f16(ai, br[jt],  acci[mt][jt], 0, 0, 0);
      }
    }
  };

  loadW(0);
  stageA(0, 0);
  writeW(0);
  __syncthreads();
#pragma unroll 2
  for (int s = 0; s < 60; ++s) {
    const int buf = s & 1;
    if (s < 59) { stageA(buf ^ 1, s + 1); loadW(s + 1); }
    compute(buf);
    if (s < 59) writeW(buf ^ 1);
    __syncthreads();
  }

  const float sc = 1.0f / (float)IMG2;
#pragma unroll
  for (int mt = 0; mt < 4; ++mt)
#pragma unroll
    for (int jt = 0; jt < 2; ++jt) {
      const int jg = j0 + w * 32 + jt * 16 + lr;
#pragma unroll
      for (int reg = 0; reg < 4; ++reg) {
        const int ig = i0 + mt * 16 + q * 4 + reg;
        float2 v = make_float2(accr[mt][jt][reg] * sc, acci[mt][jt][reg] * sc);
        *(float2*)&out[((size_t)(b * IMG_ + ig) * IMG_ + jg) * 2] = v;
      }
    }
}

// ---------------------------------------------------------------------------
// Launch: prep, fwd, comb, adj (4 kernels).
// ---------------------------------------------------------------------------
extern "C" void kernel_launch(void* const* d_in, const int* in_sizes, int n_in,
                              void* d_out, int out_size, void* d_ws, size_t ws_size,
                              hipStream_t stream) {
  (void)in_sizes; (void)n_in; (void)out_size; (void)ws_size;

  const float* xr      = (const float*)d_in[0];
  const float* xi      = (const float*)d_in[1];
  const float* samples = (const float*)d_in[2];
  const float* density = (const float*)d_in[3];
  float* out = (float*)d_out;

  // ws layout (ayh slots retired; offsets kept stable)
  _Float16* f = (_Float16*)d_ws;
  _Float16* axh_r  = f + 0 * MI_;
  _Float16* axh_i  = f + 1 * MI_;
  _Float16* axtc_r = f + 4 * MI_;
  _Float16* axtc_i = f + 5 * MI_;
  _Float16* aytc_r = f + 6 * MI_;
  _Float16* aytc_i = f + 7 * MI_;
  _Float16* kwh_r  = f + 8 * MI_;
  _Float16* kwh_i  = kwh_r + B_ * M_;

  // d_out parking: [0,16.7MB) X^T f16 (consumed by fwd_k);
  // [16.7,18.7MB) kpart f32 (consumed by comb_k); adj_k overwrites all after.
  _Float16* xth_r = (_Float16*)d_out;
  _Float16* xth_i = xth_r + (size_t)B_ * IMG2;
  float2*   kpart = (float2*)(xth_i + (size_t)B_ * IMG2);

  prep_k<<<PH1_N + PH2_N + XT_N, 256, 0, stream>>>(
      samples, xr, xi, axh_r, axh_i,
      axtc_r, axtc_i, aytc_r, aytc_i, xth_r, xth_i);
  fwd_k<<<3840, 256, 0, stream>>>(axh_r, axh_i, aytc_r, aytc_i,
                                  xth_r, xth_i, kpart);
  comb_k<<<(B_ * M_ + 255) / 256, 256, 0, stream>>>(kpart, density, kwh_r, kwh_i);
  adj_k<<<dim3(4, 2, B_), 256, 0, stream>>>(axtc_r, axtc_i, aytc_r, aytc_i,
                                            kwh_r, kwh_i, out);
}

// Round 12
// 257.716 us; speedup vs baseline: 1.0486x; 1.0063x over previous
//
#include <hip/hip_runtime.h>
#include <hip/hip_bf16.h>
#include <hip/hip_fp16.h>

// Problem constants (match reference)
constexpr int IMG_ = 256;
constexpr int M_   = 1920;   // N_SHOTS * N_SAMPLES
constexpr int B_   = 64;
constexpr int MI_  = M_ * IMG_;          // 491520 elements per phase table
constexpr int IMG2 = IMG_ * IMG_;        // 65536

typedef _Float16 half8 __attribute__((ext_vector_type(8)));
typedef float    floatx4 __attribute__((ext_vector_type(4)));

// global -> LDS direct copy, 16B per lane; LDS dest is wave-uniform base + lane*16
__device__ __forceinline__ void gll16(const _Float16* g, _Float16* l) {
  __builtin_amdgcn_global_load_lds(
      (const __attribute__((address_space(1))) void*)g,
      (__attribute__((address_space(3))) void*)l, 16, 0, 0);
}

// ---------------------------------------------------------------------------
// prep_k: fused {phase1 | phase2 | x-transpose} by blockIdx range.
// PH1 writes only the Ax table (fwd epilogue reads the transposed aytc).
// ---------------------------------------------------------------------------
constexpr int PH1_N = MI_ / 256;          // 1920
constexpr int PH2_N = 8 * IMG_;           // 2048
constexpr int XT_N  = 8 * 8 * B_;         // 4096

__global__ __launch_bounds__(256) void prep_k(
    const float* __restrict__ samples,
    const float* __restrict__ xr, const float* __restrict__ xi,
    _Float16* __restrict__ axh_r, _Float16* __restrict__ axh_i,
    _Float16* __restrict__ axtc_r, _Float16* __restrict__ axtc_i,
    _Float16* __restrict__ aytc_r, _Float16* __restrict__ aytc_i,
    _Float16* __restrict__ xth_r, _Float16* __restrict__ xth_i) {
  __shared__ float tr[32][33], ti[32][33];
  const int t = threadIdx.x;
  const int n = blockIdx.x;

  if (n < PH1_N) {
    // Ax table, natural layout [m][i] (fwd A-operand)
    int idx = n * 256 + t;
    int m = idx >> 8;
    int i = idx & 255;
    float g  = (float)i - 128.0f;
    float kx = samples[2 * m + 0];
    float sx, cx;
    sincospif(-2.0f * kx * g, &sx, &cx);
    axh_r[idx] = (_Float16)cx; axh_i[idx] = (_Float16)sx;
  } else if (n < PH1_N + PH2_N) {
    // transposed, pre-conjugated tables [i][m] (adj operands + fwd epilogue)
    int nn = n - PH1_N;
    int m = (nn & 7) * 256 + t;
    int i = nn >> 3;
    if (m < M_) {               // guard: m decode spans 2048 > M_
      float g  = (float)i - 128.0f;
      float kx = samples[2 * m + 0];
      float ky = samples[2 * m + 1];
      float sx, cx, sy, cy;
      sincospif(-2.0f * kx * g, &sx, &cx);
      sincospif(-2.0f * ky * g, &sy, &cy);
      int o = i * M_ + m;
      axtc_r[o] = (_Float16)cx; axtc_i[o] = (_Float16)(-sx);
      aytc_r[o] = (_Float16)cy; aytc_i[o] = (_Float16)(-sy);
    }
  } else {
    int nn = n - PH1_N - PH2_N;
    const int b  = nn >> 6;
    const int i0 = (nn & 7) * 32, j0 = ((nn >> 3) & 7) * 32;
    const int r = t >> 5, c = t & 31;
#pragma unroll
    for (int k = 0; k < 4; ++k) {
      int row = r + k * 8;
      tr[row][c] = xr[(size_t)b * IMG2 + (i0 + row) * IMG_ + j0 + c];
      ti[row][c] = xi[(size_t)b * IMG2 + (i0 + row) * IMG_ + j0 + c];
    }
    __syncthreads();
#pragma unroll
    for (int k = 0; k < 4; ++k) {
      int row = r + k * 8;
      xth_r[(size_t)b * IMG2 + (j0 + row) * IMG_ + i0 + c] = (_Float16)tr[c][row];
      xth_i[(size_t)b * IMG2 + (j0 + row) * IMG_ + i0 + c] = (_Float16)ti[c][row];
    }
  }
}

// ---------------------------------------------------------------------------
// LDS swizzle (both GEMMs), per 32-half (64B) row of 4 16B chunks: physical
// chunk p of row r holds logical chunk p ^ ((r>>1)&3). Staging via
// global_load_lds writes lane-linear with pre-swizzled global source;
// ds_read_b128 frags read phys chunk q ^ ((lr>>1)&3). Zero bank conflicts
// (measured every round r1-r11).
// ---------------------------------------------------------------------------

// ---------------------------------------------------------------------------
// fwd_k: converged form (r9/r11; 100.5 us steady, WRITE 21 MB benign spill).
// 8-step K-loop per jc-half (jc in grid), post-loop VECTORIZED epilogue (Ay
// from the transposed table; bit-identical since ayh_r==aytc_r, ayh_i==-aytc_i).
//   kpart[jc][b][m] = sum_{j in jc half} Ay[m,j] * (sum_i Ax[m,i] * X_b[i,j])
// Grid 3840 1-D XCD-grouped; block 64m x 128j (one jc), 8 k-steps.
// kpart now lives in ws (retired ayh slots) — NOT d_out — so the fused adj
// can read it while writing the output (no clobber race).
// ---------------------------------------------------------------------------
__global__ __launch_bounds__(256, 3) void fwd_k(
    const _Float16* __restrict__ axh_r, const _Float16* __restrict__ axh_i,
    const _Float16* __restrict__ aytc_r, const _Float16* __restrict__ aytc_i,
    const _Float16* __restrict__ xth_r, const _Float16* __restrict__ xth_i,
    float2* __restrict__ kpart) {
  __shared__ _Float16 lds[2][12288];   // 48 KB

  const int t  = threadIdx.x;
  const int w  = t >> 6;
  const int l  = t & 63;
  const int lr = l & 15;   // frag row within 16-tile; C col (j)
  const int q  = l >> 4;   // k-chunk; C row group (m)

  const int n     = blockIdx.x;        // 0..3839
  const int r     = n >> 3;            // 0..479
  const int b     = (n & 7) + 8 * (r / 60);
  const int inner = r % 60;
  const int m0    = (inner % 30) * 64;
  const int jc    = inner / 30;
  const int j0    = jc * 128;

  const int srow   = l >> 2;                      // staging row within 16
  const int schunk = (l & 3) ^ ((l >> 3) & 3);    // pre-swizzled global chunk
  const int gA     = srow * IMG_ + schunk * 8;    // halfs
  const int rc     = (q ^ ((lr >> 1) & 3)) << 3;  // frag-read swizzled chunk

  const floatx4 z4 = {0.f, 0.f, 0.f, 0.f};
  floatx4 accr[4][2], acci[4][2];
#pragma unroll
  for (int mt = 0; mt < 4; ++mt)
#pragma unroll
    for (int jt = 0; jt < 2; ++jt) { accr[mt][jt] = z4; acci[mt][jt] = z4; }

  auto stage = [&](int buf, int s) {
    const int col = s * 32;
    _Float16* L = lds[buf];
    const size_t offA = (size_t)(m0 + w * 16) * IMG_ + col + gA;
    gll16(axh_r + offA, L + 0    + w * 512);
    gll16(axh_i + offA, L + 2048 + w * 512);
    const size_t offB = (size_t)b * IMG2 + (size_t)(j0 + w * 32) * IMG_ + col + gA;
    gll16(xth_r + offB,             L + 4096 + w * 1024);
    gll16(xth_r + offB + 16 * IMG_, L + 4096 + w * 1024 + 512);
    gll16(xth_i + offB,             L + 8192 + w * 1024);
    gll16(xth_i + offB + 16 * IMG_, L + 8192 + w * 1024 + 512);
  };

  auto compute = [&](int buf) {
    const _Float16* L = lds[buf];
    half8 br[2], bi[2], nbi[2];
#pragma unroll
    for (int jt = 0; jt < 2; ++jt) {
      const int ro = (w * 32 + jt * 16 + lr) * 32 + rc;
      br[jt]  = *(const half8*)&L[4096 + ro];
      bi[jt]  = *(const half8*)&L[8192 + ro];
      nbi[jt] = -bi[jt];
    }
#pragma unroll
    for (int mt = 0; mt < 4; ++mt) {
      const int ro = (mt * 16 + lr) * 32 + rc;
      half8 ar = *(const half8*)&L[0 + ro];
      half8 ai = *(const half8*)&L[2048 + ro];
#pragma unroll
      for (int jt = 0; jt < 2; ++jt) {
        accr[mt][jt] = __builtin_amdgcn_mfma_f32_16x16x32_f16(ar, br[jt],  accr[mt][jt], 0, 0, 0);
        accr[mt][jt] = __builtin_amdgcn_mfma_f32_16x16x32_f16(ai, nbi[jt], accr[mt][jt], 0, 0, 0);
        acci[mt][jt] = __builtin_amdgcn_mfma_f32_16x16x32_f16(ar, bi[jt],  acci[mt][jt], 0, 0, 0);
        acci[mt][jt] = __builtin_amdgcn_mfma_f32_16x16x32_f16(ai, br[jt],  acci[mt][jt], 0, 0, 0);
      }
    }
  };

  stage(0, 0);
  __syncthreads();               // implicit vmcnt(0) drains global_load_lds
#pragma unroll
  for (int s = 0; s < 8; ++s) {
    const int buf = s & 1;
    if (s < 7) stage(buf ^ 1, s + 1);    // next-tile loads overlap MFMA
    compute(buf);
    __syncthreads();
  }

  // Epilogue (once, post-loop): kacc[m] += sum_j Ay[m,j]*T[m,j]
  // Ay via transposed table: yr = aytc_r[j][m..m+3], yi = -aytc_i[j][m..m+3]
  float kr[4][4] = {}, ki[4][4] = {};
#pragma unroll
  for (int mt = 0; mt < 4; ++mt) {
    const int mb = m0 + mt * 16 + q * 4;
#pragma unroll
    for (int jt = 0; jt < 2; ++jt) {
      const int j = j0 + w * 32 + jt * 16 + lr;
      const __half2* yr2 = (const __half2*)&aytc_r[(size_t)j * M_ + mb];
      const __half2* yi2 = (const __half2*)&aytc_i[(size_t)j * M_ + mb];
      const __half2 yr01 = yr2[0], yr23 = yr2[1];
      const __half2 yi01 = yi2[0], yi23 = yi2[1];
      const float yrv[4] = {__low2float(yr01), __high2float(yr01),
                            __low2float(yr23), __high2float(yr23)};
      const float yiv[4] = {-__low2float(yi01), -__high2float(yi01),
                            -__low2float(yi23), -__high2float(yi23)};
#pragma unroll
      for (int reg = 0; reg < 4; ++reg) {
        const float tr = accr[mt][jt][reg], ti = acci[mt][jt][reg];
        kr[mt][reg] = fmaf(yrv[reg], tr, fmaf(-yiv[reg], ti, kr[mt][reg]));
        ki[mt][reg] = fmaf(yrv[reg], ti, fmaf(yiv[reg], tr, ki[mt][reg]));
      }
    }
  }

#pragma unroll
  for (int mt = 0; mt < 4; ++mt)
#pragma unroll
    for (int reg = 0; reg < 4; ++reg)
#pragma unroll
      for (int off = 1; off < 16; off <<= 1) {
        kr[mt][reg] += __shfl_xor(kr[mt][reg], off);
        ki[mt][reg] += __shfl_xor(ki[mt][reg], off);
      }

  float2* scr = (float2*)&lds[0][0];
  if (lr == 0) {
#pragma unroll
    for (int mt = 0; mt < 4; ++mt)
#pragma unroll
      for (int reg = 0; reg < 4; ++reg)
        scr[w * 64 + mt * 16 + q * 4 + reg] = make_float2(kr[mt][reg], ki[mt][reg]);
  }
  __syncthreads();
  if (t < 64) {
    float sr = 0.f, si = 0.f;
#pragma unroll
    for (int ww = 0; ww < 4; ++ww) {
      const float2 p = scr[ww * 64 + t];
      sr += p.x; si += p.y;
    }
    kpart[((size_t)jc * B_ + b) * M_ + m0 + t] = make_float2(sr, si);
  }
}

// ---------------------------------------------------------------------------
// adj_k: r3 GEMM structure + FUSED comb prologue (round 12).
//   kw[b,m] = density[m] * (kpart[0][b][m] + kpart[1][b][m])   (per-block LDS)
//   out[b,i,j] = (1/IMG^2) sum_m conj(Ax)[m,i] * kw[b,m] * conj(Ay)[m,j]
// Each block computes its own f16 kw[b,:] copy into LDS (7.5 KB; 1920x2 elems
// over 256 threads, ~2 us) — eliminates comb_k + its launch gap. writeW reads
// Cr/Ci from LDS (2 distinct 16B addrs/wave, 32-lane broadcast = free).
// LDS 48 -> 55.5 KB: occupancy stays 2 blocks/CU (grid 512 = 2/CU already).
// Numerics identical to comb_k (same f32 sum, density mult, f16 convert).
// Block 256 thr = 4 waves; block tile 64i x 128j; wave tile 64i x 32j.
// K = 1920 m, 60 double-buffered steps. Grid (4, 2, 64) = 512 blocks.
// ---------------------------------------------------------------------------
__global__ __launch_bounds__(256, 3) void adj_k(
    const _Float16* __restrict__ axtc_r, const _Float16* __restrict__ axtc_i,
    const _Float16* __restrict__ aytc_r, const _Float16* __restrict__ aytc_i,
    const float2* __restrict__ kpart, const float* __restrict__ density,
    float* __restrict__ out) {
  __shared__ _Float16 lds[2][12288];   // 48 KB staging
  __shared__ _Float16 kwl[2][M_];      // 7.5 KB: block-local kw (r, i)

  const int t  = threadIdx.x;
  const int w  = t >> 6;
  const int l  = t & 63;
  const int lr = l & 15;
  const int q  = l >> 4;
  const int b  = blockIdx.z;
  const int i0 = blockIdx.x * 64;
  const int j0 = blockIdx.y * 128;

  // ---- fused comb prologue: kw[b,:] -> LDS (read-only afterwards) ----
#pragma unroll
  for (int it = 0; it < 8; ++it) {
    const int m = it * 256 + t;
    if (m < M_) {
      const float2 p0 = kpart[(size_t)b * M_ + m];
      const float2 p1 = kpart[(size_t)(B_ + b) * M_ + m];
      const float d = density[m];
      kwl[0][m] = (_Float16)((p0.x + p1.x) * d);
      kwl[1][m] = (_Float16)((p0.y + p1.y) * d);
    }
  }

  const int srow   = l >> 2;
  const int schunk = (l & 3) ^ ((l >> 3) & 3);
  const int gA     = srow * M_ + schunk * 8;      // A row stride = 1920 halfs
  const int rc     = (q ^ ((lr >> 1) & 3)) << 3;

  // W staging: thread -> (j-row = t>>1, m-half = t&1); swizzled b128 writes
  const int wrow = t >> 1;
  const int wh   = t & 1;
  const int wp   = (wrow >> 1) & 3;
  const int wc0  = ((2 * wh + 0) ^ wp) << 3;
  const int wc1  = ((2 * wh + 1) ^ wp) << 3;

  const floatx4 z4 = {0.f, 0.f, 0.f, 0.f};
  floatx4 accr[4][2], acci[4][2];
#pragma unroll
  for (int mt = 0; mt < 4; ++mt)
#pragma unroll
    for (int jt = 0; jt < 2; ++jt) { accr[mt][jt] = z4; acci[mt][jt] = z4; }

  uint4 Yr0, Yr1, Yi0, Yi1;

  auto stageA = [&](int buf, int s) {
    const int mc = s * 32;
    _Float16* L = lds[buf];
    const size_t off = (size_t)(i0 + w * 16) * M_ + mc + gA;
    gll16(axtc_r + off, L + 0    + w * 512);
    gll16(axtc_i + off, L + 2048 + w * 512);
  };

  auto loadW = [&](int s) {   // issue Ay loads early; kw comes from LDS
    const int mc = s * 32 + wh * 16;
    const size_t oy = (size_t)(j0 + wrow) * M_ + mc;
    Yr0 = *(const uint4*)&aytc_r[oy];  Yr1 = *(const uint4*)&aytc_r[oy + 8];
    Yi0 = *(const uint4*)&aytc_i[oy];  Yi1 = *(const uint4*)&aytc_i[oy + 8];
  };

  auto writeW = [&](int buf, int s) {
    const int mc = s * 32 + wh * 16;
    const uint4 Cr0 = *(const uint4*)&kwl[0][mc];
    const uint4 Cr1 = *(const uint4*)&kwl[0][mc + 8];
    const uint4 Ci0 = *(const uint4*)&kwl[1][mc];
    const uint4 Ci1 = *(const uint4*)&kwl[1][mc + 8];
    __half2 Wr0[4], Wi0[4], Wr1[4], Wi1[4];
    {
      const __half2* yr = (const __half2*)&Yr0; const __half2* yi = (const __half2*)&Yi0;
      const __half2* cr = (const __half2*)&Cr0; const __half2* ci = (const __half2*)&Ci0;
#pragma unroll
      for (int e = 0; e < 4; ++e) {
        Wr0[e] = __hsub2(__hmul2(cr[e], yr[e]), __hmul2(ci[e], yi[e]));
        Wi0[e] = __hfma2(cr[e], yi[e], __hmul2(ci[e], yr[e]));
      }
    }
    {
      const __half2* yr = (const __half2*)&Yr1; const __half2* yi = (const __half2*)&Yi1;
      const __half2* cr = (const __half2*)&Cr1; const __half2* ci = (const __half2*)&Ci1;
#pragma unroll
      for (int e = 0; e < 4; ++e) {
        Wr1[e] = __hsub2(__hmul2(cr[e], yr[e]), __hmul2(ci[e], yi[e]));
        Wi1[e] = __hfma2(cr[e], yi[e], __hmul2(ci[e], yr[e]));
      }
    }
    _Float16* Lr = lds[buf] + 4096;
    _Float16* Li = lds[buf] + 8192;
    const int rb = wrow * 32;
    *(uint4*)&Lr[rb + wc0] = *(const uint4*)&Wr0[0];
    *(uint4*)&Lr[rb + wc1] = *(const uint4*)&Wr1[0];
    *(uint4*)&Li[rb + wc0] = *(const uint4*)&Wi0[0];
    *(uint4*)&Li[rb + wc1] = *(const uint4*)&Wi1[0];
  };

  auto compute = [&](int buf) {
    const _Float16* L = lds[buf];
    half8 br[2], bi[2], nbi[2];
#pragma unroll
    for (int jt = 0; jt < 2; ++jt) {
      const int ro = (w * 32 + jt * 16 + lr) * 32 + rc;
      br[jt]  = *(const half8*)&L[4096 + ro];
      bi[jt]  = *(const half8*)&L[8192 + ro];
      nbi[jt] = -bi[jt];
    }
#pragma unroll
    for (int mt = 0; mt < 4; ++mt) {
      const int ro = (mt * 16 + lr) * 32 + rc;
      half8 ar = *(const half8*)&L[0 + ro];
      half8 ai = *(const half8*)&L[2048 + ro];
#pragma unroll
      for (int jt = 0; jt < 2; ++jt) {
        accr[mt][jt] = __builtin_amdgcn_mfma_f32_16x16x32_f16(ar, br[jt],  accr[mt][jt], 0, 0, 0);
        accr[mt][jt] = __builtin_amdgcn_mfma_f32_16x16x32_f16(ai, nbi[jt], accr[mt][jt], 0, 0, 0);
        acci[mt][jt] = __builtin_amdgcn_mfma_f32_16x16x32_f16(ar, bi[jt],  acci[mt][jt], 0, 0, 0);
        acci[mt][jt] = __builtin_amdgcn_mfma_f32_16x16x32_f16(ai, br[jt],  acci[mt][jt], 0, 0, 0);
      }
    }
  };

  loadW(0);
  stageA(0, 0);
  __syncthreads();               // kw LDS ready + staged A drained
  writeW(0, 0);
  __syncthreads();               // W(0) visible before compute(0)
#pragma unroll 2
  for (int s = 0; s < 60; ++s) {
    const int buf = s & 1;
    if (s < 59) { stageA(buf ^ 1, s + 1); loadW(s + 1); }
    compute(buf);
    if (s < 59) writeW(buf ^ 1, s + 1);
    __syncthreads();
  }

  const float sc = 1.0f / (float)IMG2;
#pragma unroll
  for (int mt = 0; mt < 4; ++mt)
#pragma unroll
    for (int jt = 0; jt < 2; ++jt) {
      const int jg = j0 + w * 32 + jt * 16 + lr;
#pragma unroll
      for (int reg = 0; reg < 4; ++reg) {
        const int ig = i0 + mt * 16 + q * 4 + reg;
        float2 v = make_float2(accr[mt][jt][reg] * sc, acci[mt][jt][reg] * sc);
        *(float2*)&out[((size_t)(b * IMG_ + ig) * IMG_ + jg) * 2] = v;
      }
    }
}

// ---------------------------------------------------------------------------
// Launch: prep, fwd, adj (3 kernels; comb_k fused into adj prologue).
// ---------------------------------------------------------------------------
extern "C" void kernel_launch(void* const* d_in, const int* in_sizes, int n_in,
                              void* d_out, int out_size, void* d_ws, size_t ws_size,
                              hipStream_t stream) {
  (void)in_sizes; (void)n_in; (void)out_size; (void)ws_size;

  const float* xr      = (const float*)d_in[0];
  const float* xi      = (const float*)d_in[1];
  const float* samples = (const float*)d_in[2];
  const float* density = (const float*)d_in[3];
  float* out = (float*)d_out;

  // ws layout: kpart lives in the retired ayh slots (f+2MI_ .. f+4MI_,
  // exactly 2*64*1920*8B = 1.97 MB) so adj can read it while writing d_out.
  _Float16* f = (_Float16*)d_ws;
  _Float16* axh_r  = f + 0 * MI_;
  _Float16* axh_i  = f + 1 * MI_;
  float2*   kpart  = (float2*)(f + 2 * MI_);
  _Float16* axtc_r = f + 4 * MI_;
  _Float16* axtc_i = f + 5 * MI_;
  _Float16* aytc_r = f + 6 * MI_;
  _Float16* aytc_i = f + 7 * MI_;

  // X^T (f16) parked in d_out; fully consumed by fwd_k before adj_k overwrites.
  _Float16* xth_r = (_Float16*)d_out;
  _Float16* xth_i = xth_r + (size_t)B_ * IMG2;

  prep_k<<<PH1_N + PH2_N + XT_N, 256, 0, stream>>>(
      samples, xr, xi, axh_r, axh_i,
      axtc_r, axtc_i, aytc_r, aytc_i, xth_r, xth_i);
  fwd_k<<<3840, 256, 0, stream>>>(axh_r, axh_i, aytc_r, aytc_i,
                                  xth_r, xth_i, kpart);
  adj_k<<<dim3(4, 2, B_), 256, 0, stream>>>(axtc_r, axtc_i, aytc_r, aytc_i,
                                            kpart, density, out);
}